// Round 1
// baseline (1411.527 us; speedup 1.0000x reference)
//
#include <hip/hip_runtime.h>
#include <hip/hip_bf16.h>

#define NBLK 4096
#define BS 32
#define CH 128
#define NH 4
#define HD 32

typedef float f32x4 __attribute__((ext_vector_type(4)));
typedef short bf16x8 __attribute__((ext_vector_type(8)));   // 8 bf16 (4 VGPRs)
typedef unsigned short u16x4 __attribute__((ext_vector_type(4)));

__device__ __forceinline__ short f2b(float x) {
    union { float f; unsigned u; } c; c.f = x;
    unsigned r = c.u + 0x7fffu + ((c.u >> 16) & 1u);
    return (short)(r >> 16);
}

// --- pre-kernel: convert weights to bf16 into workspace -------------------
__global__ void convert_weights(const float* __restrict__ wqkv,
                                const float* __restrict__ wproj,
                                short* __restrict__ wsout) {
    int i = blockIdx.x * 256 + threadIdx.x;          // 0 .. 65535
    if (i < 3 * CH * CH) {
        wsout[i] = f2b(wqkv[i]);
    } else {
        int j = i - 3 * CH * CH;
        if (j < CH * CH) wsout[3 * CH * CH + j] = f2b(wproj[j]);
    }
}

// --- main fused kernel: one workgroup per 32-token block ------------------
union U1 { float xf[32][132]; float comb[32][4][33]; };
union U2 { short kvb[48][136]; short xob[32][136]; };

__launch_bounds__(256, 2)
__global__ void fused_block_attn(
    const float* __restrict__ x,
    const float* __restrict__ edge_feats,
    const float* __restrict__ bqkv,
    const float* __restrict__ bproj,
    const float* __restrict__ wgate,
    const float* __restrict__ bgate,
    const int*   __restrict__ attn_mask,
    const short* __restrict__ wqkv_b,    // [384][128] bf16
    const short* __restrict__ wproj_b,   // [128][128] bf16
    float* __restrict__ out)
{
    const int b    = blockIdx.x;
    const int tid  = threadIdx.x;
    const int lane = tid & 63;
    const int w    = tid >> 6;

    __shared__ U1 u1;                    // 16896 B
    __shared__ U2 u2;                    // 13056 B
    __shared__ float qs[32][132];        // 16896 B
    __shared__ float ks[33][132];        // 17424 B
    __shared__ float vs[33][132];        // 17424 B   -> total 81696 B

    // ---------------- Phase 0: stage x, block mean, kv -> bf16 ------------
    const float* xb = x + (size_t)b * BS * CH;
    #pragma unroll
    for (int it = 0; it < 4; ++it) {
        int idx = tid + it * 256;        // float4 index, 0..1023
        int r   = idx >> 5;
        int c4  = (idx & 31);
        f32x4 t = ((const f32x4*)xb)[idx];
        *(f32x4*)&u1.xf[r][c4 * 4] = t;
        u16x4 hb;
        hb[0] = (unsigned short)f2b(t[0]);
        hb[1] = (unsigned short)f2b(t[1]);
        hb[2] = (unsigned short)f2b(t[2]);
        hb[3] = (unsigned short)f2b(t[3]);
        *(u16x4*)&u2.kvb[r][c4 * 4] = hb;
    }
    __syncthreads();
    if (tid < CH) {
        float s = 0.f;
        #pragma unroll
        for (int r = 0; r < BS; ++r) s += u1.xf[r][tid];
        u2.kvb[32][tid] = f2b(s * (1.0f / BS));
    }
    __syncthreads();

    // ---------------- Phase 1: QKV = kv @ Wqkv^T (MFMA bf16) --------------
    const int am   = lane & 15;          // A row within tile
    const int ak   = (lane >> 4) << 3;   // A/B k-offset within 32
    const int colm = lane & 15;          // D column within tile

    bf16x8 afr[3][4];
    #pragma unroll
    for (int mi = 0; mi < 3; ++mi)
        #pragma unroll
        for (int kk = 0; kk < 4; ++kk)
            afr[mi][kk] = *(const bf16x8*)&u2.kvb[mi * 16 + am][kk * 32 + ak];

    {
        const int nt0 = w * 6;           // 6 n-tiles of 16 per wave, 24 total
        bf16x8 bcur[4], bnext[4];
        const short* wq0 = wqkv_b + ((nt0 * 16 + colm) * CH + ak);
        #pragma unroll
        for (int kk = 0; kk < 4; ++kk) bcur[kk] = *(const bf16x8*)(wq0 + kk * 32);

        #pragma unroll
        for (int ntl = 0; ntl < 6; ++ntl) {
            int nt = nt0 + ntl;
            if (ntl < 5) {
                const short* wqn = wqkv_b + (((nt + 1) * 16 + colm) * CH + ak);
                #pragma unroll
                for (int kk = 0; kk < 4; ++kk) bnext[kk] = *(const bf16x8*)(wqn + kk * 32);
            }
            int o0 = nt * 16;
            float bias = bqkv[o0 + colm];
            f32x4 acc0 = {bias, bias, bias, bias};
            f32x4 acc1 = acc0, acc2 = acc0;
            #pragma unroll
            for (int kk = 0; kk < 4; ++kk) {
                acc0 = __builtin_amdgcn_mfma_f32_16x16x32_bf16(afr[0][kk], bcur[kk], acc0, 0, 0, 0);
                acc1 = __builtin_amdgcn_mfma_f32_16x16x32_bf16(afr[1][kk], bcur[kk], acc1, 0, 0, 0);
                acc2 = __builtin_amdgcn_mfma_f32_16x16x32_bf16(afr[2][kk], bcur[kk], acc2, 0, 0, 0);
            }
            int rb = (lane >> 4) * 4;
            #pragma unroll
            for (int j = 0; j < 4; ++j) {
                int r0 = rb + j;
                if (nt < 8) {                       // q columns 0..127
                    qs[r0][o0 + colm]      = acc0[j];
                    qs[16 + r0][o0 + colm] = acc1[j];
                } else if (nt < 16) {               // k columns
                    int cc = o0 - 128 + colm;
                    ks[r0][cc]      = acc0[j];
                    ks[16 + r0][cc] = acc1[j];
                    if (r0 == 0) ks[32][cc] = acc2[j];
                } else {                            // v columns
                    int cc = o0 - 256 + colm;
                    vs[r0][cc]      = acc0[j];
                    vs[16 + r0][cc] = acc1[j];
                    if (r0 == 0) vs[32][cc] = acc2[j];
                }
            }
            #pragma unroll
            for (int kk = 0; kk < 4; ++kk) bcur[kk] = bnext[kk];
        }
    }
    __syncthreads();

    // ---------------- Phase 2: scores, softmax, edge gate (f32) -----------
    if (tid < 128) {
        const int r = tid >> 2;
        const int h = tid & 3;
        f32x4 qv[8];
        #pragma unroll
        for (int c4 = 0; c4 < 8; ++c4)
            qv[c4] = *(const f32x4*)&qs[r][h * 32 + c4 * 4];

        const float* efb = edge_feats + ((size_t)(b * BS + r)) * 33 * 4;
        const int*   mkb = attn_mask + (size_t)(b * BS + r) * 33;
        f32x4 wg = *(const f32x4*)(wgate + h * 4);
        float bg = bgate[h];

        float sc[33];
        float mx = -3.0e38f;
        #pragma unroll
        for (int s = 0; s < 33; ++s) {
            f32x4 a = {0.f, 0.f, 0.f, 0.f};
            #pragma unroll
            for (int c4 = 0; c4 < 8; ++c4) {
                f32x4 kvv = *(const f32x4*)&ks[s][h * 32 + c4 * 4];
                a += qv[c4] * kvv;
            }
            float dot = (a[0] + a[1]) + (a[2] + a[3]);
            f32x4 ef;
            if (s == 32 || s == r) { ef[0] = 0.f; ef[1] = 0.f; ef[2] = 0.f; ef[3] = 1.f; }
            else                   ef = *(const f32x4*)(efb + s * 4);
            int m = mkb[s];
            float sv = dot * 0.17677669529663689f + ef[3];
            sc[s] = m ? sv : -1e30f;
            mx = fmaxf(mx, sc[s]);
            float lew = m ? (ef[0] * wg[0] + ef[1] * wg[1] + ef[2] * wg[2] + ef[3] * wg[3] + bg) : 0.f;
            u1.comb[r][h][s] = lew;     // combined = lew (+ prob later)
        }
        float sum = 0.f;
        #pragma unroll
        for (int s = 0; s < 33; ++s) {
            float e = __expf(sc[s] - mx);
            sc[s] = e;
            sum += e;
        }
        float rinv = 1.f / sum;
        #pragma unroll
        for (int s = 0; s < 33; ++s)
            u1.comb[r][h][s] += sc[s] * rinv;
    }
    __syncthreads();

    // ---------------- Phase 3: x_out = combined @ v (f32), store bf16 -----
    {
        const int r    = tid >> 3;
        const int h    = (tid >> 1) & 3;
        const int half = tid & 1;
        const int cb   = h * 32 + half * 16;
        f32x4 acc[4] = {};
        #pragma unroll
        for (int s = 0; s < 33; ++s) {
            float cmb = u1.comb[r][h][s];
            #pragma unroll
            for (int c4 = 0; c4 < 4; ++c4) {
                f32x4 vv = *(const f32x4*)&vs[s][cb + c4 * 4];
                acc[c4] += cmb * vv;
            }
        }
        #pragma unroll
        for (int c4 = 0; c4 < 4; ++c4) {
            u16x4 hb;
            hb[0] = (unsigned short)f2b(acc[c4][0]);
            hb[1] = (unsigned short)f2b(acc[c4][1]);
            hb[2] = (unsigned short)f2b(acc[c4][2]);
            hb[3] = (unsigned short)f2b(acc[c4][3]);
            *(u16x4*)&u2.xob[r][cb + c4 * 4] = hb;
        }
    }
    __syncthreads();

    // ---------------- Phase 4: out = x_out @ Wproj^T + bproj (MFMA) -------
    {
        bf16x8 a2[2][4];
        #pragma unroll
        for (int mi = 0; mi < 2; ++mi)
            #pragma unroll
            for (int kk = 0; kk < 4; ++kk)
                a2[mi][kk] = *(const bf16x8*)&u2.xob[mi * 16 + am][kk * 32 + ak];

        float* ob = out + (size_t)b * BS * CH;
        #pragma unroll
        for (int ntl = 0; ntl < 2; ++ntl) {
            int o0  = (w * 2 + ntl) * 16;
            int col = o0 + colm;
            float bias = bproj[col];
            f32x4 acc0 = {bias, bias, bias, bias};
            f32x4 acc1 = acc0;
            #pragma unroll
            for (int kk = 0; kk < 4; ++kk) {
                bf16x8 bfr = *(const bf16x8*)(wproj_b + col * CH + kk * 32 + ak);
                acc0 = __builtin_amdgcn_mfma_f32_16x16x32_bf16(a2[0][kk], bfr, acc0, 0, 0, 0);
                acc1 = __builtin_amdgcn_mfma_f32_16x16x32_bf16(a2[1][kk], bfr, acc1, 0, 0, 0);
            }
            int rb = (lane >> 4) * 4;
            #pragma unroll
            for (int j = 0; j < 4; ++j) {
                ob[(rb + j) * CH + col]        = acc0[j];
                ob[(16 + rb + j) * CH + col]   = acc1[j];
            }
        }
    }
}

extern "C" void kernel_launch(void* const* d_in, const int* in_sizes, int n_in,
                              void* d_out, int out_size, void* d_ws, size_t ws_size,
                              hipStream_t stream) {
    const float* x          = (const float*)d_in[0];
    const float* edge_feats = (const float*)d_in[1];
    const float* Wqkv       = (const float*)d_in[2];
    const float* bqkv       = (const float*)d_in[3];
    const float* Wproj      = (const float*)d_in[4];
    const float* bproj      = (const float*)d_in[5];
    const float* Wgate      = (const float*)d_in[6];
    const float* bgate      = (const float*)d_in[7];
    const int*   attn_mask  = (const int*)d_in[8];
    float* out = (float*)d_out;
    short* wb  = (short*)d_ws;

    convert_weights<<<256, 256, 0, stream>>>(Wqkv, Wproj, wb);
    fused_block_attn<<<NBLK, 256, 0, stream>>>(
        x, edge_feats, bqkv, bproj, Wgate, bgate, attn_mask,
        wb, wb + 3 * CH * CH, out);
}

// Round 2
// 149.106 us; speedup vs baseline: 9.4666x; 9.4666x over previous
//
#include <hip/hip_runtime.h>
#include <hip/hip_bf16.h>

#define NBLK 4096
#define BS 32
#define CH 128
#define NH 4
#define HD 32

typedef float f32x4 __attribute__((ext_vector_type(4)));
typedef short bf16x8 __attribute__((ext_vector_type(8)));
typedef unsigned short u16x4 __attribute__((ext_vector_type(4)));

__device__ __forceinline__ short f2b(float x) {
    union { float f; unsigned u; } c; c.f = x;
    unsigned r = c.u + 0x7fffu + ((c.u >> 16) & 1u);
    return (short)(r >> 16);
}
__device__ __forceinline__ float b2f(unsigned short h) {
    union { unsigned u; float f; } c; c.u = ((unsigned)h) << 16; return c.f;
}

// --- pre-kernel: convert weights to bf16 into workspace -------------------
__global__ void convert_weights(const float* __restrict__ wqkv,
                                const float* __restrict__ wproj,
                                short* __restrict__ wsout) {
    int i = blockIdx.x * 256 + threadIdx.x;          // 0 .. 65535
    if (i < 3 * CH * CH) {
        wsout[i] = f2b(wqkv[i]);
    } else {
        int j = i - 3 * CH * CH;
        if (j < CH * CH) wsout[3 * CH * CH + j] = f2b(wproj[j]);
    }
}

// --- main fused kernel: one workgroup per 32-token block ------------------
// LDS plan (36,960 B total -> 4 blocks/CU):
//   region1 [33][136] bf16 (8976 B): kv-staging -> q (rows 0-31) -> comb
//           (comb row r overlays q row r exactly; kv row 32 = mean, persistent)
//   ksh [4][33][36] f32 (19008 B): mean-partials (phase 0) -> K per head -> x_out bf16
//   vsh [33][136] bf16 (8976 B): V
__launch_bounds__(256, 4)
__global__ void fused_block_attn(
    const float* __restrict__ x,
    const float* __restrict__ edge_feats,
    const float* __restrict__ bqkv,
    const float* __restrict__ bproj,
    const float* __restrict__ wgate,
    const float* __restrict__ bgate,
    const int*   __restrict__ attn_mask,
    const short* __restrict__ wqkv_b,    // [384][128] bf16
    const short* __restrict__ wproj_b,   // [128][128] bf16
    float* __restrict__ out)
{
    const int b    = blockIdx.x;
    const int tid  = threadIdx.x;
    const int lane = tid & 63;
    const int w    = tid >> 6;

    __shared__ short region1[33 * 136];
    __shared__ float ksh[NH][33][36];
    __shared__ short vsh[33 * 136];

    short* kvb  = region1;               // [33][136] bf16
    short* qb   = region1;               // [32][136] bf16 (phase 1+)
    short* comb = region1;               // [32][4][34] bf16: r*136 + h*34 + s
    float* partials = (float*)ksh;       // [8][132] f32 (phase 0 only)
    short* xob  = (short*)ksh;           // [32][136] bf16 (phase 3+)

    // ---------------- Phase 0: stage x (bf16), column partial sums --------
    const float* xb = x + (size_t)b * BS * CH;
    {
        const int c4 = tid & 31;
        f32x4 psum = {0.f, 0.f, 0.f, 0.f};
        #pragma unroll
        for (int it = 0; it < 4; ++it) {
            int idx = tid + it * 256;
            int r   = idx >> 5;
            f32x4 t = ((const f32x4*)xb)[idx];
            psum += t;
            u16x4 hb;
            hb[0] = (unsigned short)f2b(t[0]);
            hb[1] = (unsigned short)f2b(t[1]);
            hb[2] = (unsigned short)f2b(t[2]);
            hb[3] = (unsigned short)f2b(t[3]);
            *(u16x4*)&kvb[r * 136 + c4 * 4] = hb;
        }
        *(f32x4*)&partials[(tid >> 5) * 132 + c4 * 4] = psum;
    }
    __syncthreads();
    if (tid < CH) {
        float s = 0.f;
        #pragma unroll
        for (int p = 0; p < 8; ++p) s += partials[p * 132 + tid];
        kvb[32 * 136 + tid] = f2b(s * (1.0f / BS));
    }
    __syncthreads();

    // ---------------- Phase 1: QKV = kv @ Wqkv^T (MFMA bf16) --------------
    const int am   = lane & 15;
    const int ak   = (lane >> 4) << 3;
    const int colm = lane & 15;
    const int rb   = (lane >> 4) * 4;

    bf16x8 afr[3][4];
    #pragma unroll
    for (int kk = 0; kk < 4; ++kk) {
        afr[0][kk] = *(const bf16x8*)&kvb[am * 136 + kk * 32 + ak];
        afr[1][kk] = *(const bf16x8*)&kvb[(16 + am) * 136 + kk * 32 + ak];
        afr[2][kk] = *(const bf16x8*)&kvb[32 * 136 + kk * 32 + ak]; // mean row bcast
    }
    __syncthreads();   // all A-frags in regs; q may now overwrite kv rows 0-31

    for (int ntl = 0; ntl < 6; ++ntl) {
        const int nt = w * 6 + ntl;
        const int o0 = nt * 16;
        const short* wq = wqkv_b + (o0 + colm) * CH + ak;
        bf16x8 bcur[4];
        #pragma unroll
        for (int kk = 0; kk < 4; ++kk) bcur[kk] = *(const bf16x8*)(wq + kk * 32);
        float bias = bqkv[o0 + colm];
        f32x4 acc0 = {bias, bias, bias, bias};
        f32x4 acc1 = acc0, acc2 = acc0;
        #pragma unroll
        for (int kk = 0; kk < 4; ++kk) {
            acc0 = __builtin_amdgcn_mfma_f32_16x16x32_bf16(afr[0][kk], bcur[kk], acc0, 0, 0, 0);
            acc1 = __builtin_amdgcn_mfma_f32_16x16x32_bf16(afr[1][kk], bcur[kk], acc1, 0, 0, 0);
            acc2 = __builtin_amdgcn_mfma_f32_16x16x32_bf16(afr[2][kk], bcur[kk], acc2, 0, 0, 0);
        }
        if (nt < 8) {                         // q columns 0..127 -> bf16
            #pragma unroll
            for (int j = 0; j < 4; ++j) {
                qb[(rb + j) * 136 + o0 + colm]      = f2b(acc0[j]);
                qb[(16 + rb + j) * 136 + o0 + colm] = f2b(acc1[j]);
            }
        } else if (nt < 16) {                 // k columns -> f32 per-head
            int cc = o0 - 128 + colm;
            int h = cc >> 5, d = cc & 31;
            #pragma unroll
            for (int j = 0; j < 4; ++j) {
                ksh[h][rb + j][d]      = acc0[j];
                ksh[h][16 + rb + j][d] = acc1[j];
            }
            if (rb == 0) ksh[h][32][d] = acc2[0];
        } else {                              // v columns -> bf16
            int cc = o0 - 256 + colm;
            #pragma unroll
            for (int j = 0; j < 4; ++j) {
                vsh[(rb + j) * 136 + cc]      = f2b(acc0[j]);
                vsh[(16 + rb + j) * 136 + cc] = f2b(acc1[j]);
            }
            if (rb == 0) vsh[32 * 136 + cc] = f2b(acc2[0]);
        }
    }
    __syncthreads();

    // ---------------- Phase 2: scores -> softmax -> +edge gate (rolled) ---
    if (tid < 128) {
        const int r = tid >> 2;
        const int h = tid & 3;
        f32x4 qv4[8];
        #pragma unroll
        for (int k8 = 0; k8 < 4; ++k8) {
            bf16x8 t = *(const bf16x8*)&qb[r * 136 + h * 32 + k8 * 8];
            f32x4 lo, hi;
            #pragma unroll
            for (int j = 0; j < 4; ++j) { lo[j] = b2f((unsigned short)t[j]); hi[j] = b2f((unsigned short)t[4 + j]); }
            qv4[k8 * 2]     = lo;
            qv4[k8 * 2 + 1] = hi;
        }
        const float* efb = edge_feats + (size_t)(b * BS + r) * 33 * 4;
        const int*   mkb = attn_mask + (size_t)(b * BS + r) * 33;
        short* cmb = &comb[r * 136 + h * 34];

        float mx = -3.0e38f;
        #pragma unroll 3
        for (int s = 0; s < 33; ++s) {
            float efw = efb[s * 4 + 3];
            if (s >= 32 || s == r) efw = 1.0f;
            int m = mkb[s];
            const float* kr = &ksh[h][s][0];
            f32x4 a = {0.f, 0.f, 0.f, 0.f};
            #pragma unroll
            for (int c = 0; c < 8; ++c) a += qv4[c] * (*(const f32x4*)(kr + c * 4));
            float dot = (a[0] + a[1]) + (a[2] + a[3]);
            float sc = m ? (dot * 0.17677669529663689f + efw) : -1.0e30f;
            mx = fmaxf(mx, sc);
            cmb[s] = f2b(sc);
        }
        float sum = 0.f;
        #pragma unroll 3
        for (int s = 0; s < 33; ++s) {
            float e = __expf(b2f((unsigned short)cmb[s]) - mx);
            sum += e;
            cmb[s] = f2b(e);
        }
        float rinv = 1.0f / sum;
        f32x4 wg = *(const f32x4*)(wgate + h * 4);
        float bg = bgate[h];
        #pragma unroll 3
        for (int s = 0; s < 33; ++s) {
            int m = mkb[s];
            f32x4 ef = *(const f32x4*)(efb + s * 4);
            if (s >= 32 || s == r) { ef[0] = 0.f; ef[1] = 0.f; ef[2] = 0.f; ef[3] = 1.f; }
            float lew = ef[0] * wg[0] + ef[1] * wg[1] + ef[2] * wg[2] + ef[3] * wg[3] + bg;
            float e = b2f((unsigned short)cmb[s]);
            float val = e * rinv + (m ? lew : 0.f);
            cmb[s] = f2b(val);
        }
    }
    __syncthreads();

    // ---------------- Phase 3: x_out = combined @ v (rolled, bf16 in) -----
    {
        const int r    = tid >> 3;
        const int h    = (tid >> 1) & 3;
        const int half = tid & 1;
        const int cb   = h * 32 + half * 16;
        const short* cmb = &comb[r * 136 + h * 34];
        f32x4 acc[4] = {};
        #pragma unroll 3
        for (int s = 0; s < 33; ++s) {
            float cv = b2f((unsigned short)cmb[s]);
            bf16x8 v0 = *(const bf16x8*)&vsh[s * 136 + cb];
            bf16x8 v1 = *(const bf16x8*)&vsh[s * 136 + cb + 8];
            #pragma unroll
            for (int j = 0; j < 4; ++j) acc[0][j] += cv * b2f((unsigned short)v0[j]);
            #pragma unroll
            for (int j = 0; j < 4; ++j) acc[1][j] += cv * b2f((unsigned short)v0[4 + j]);
            #pragma unroll
            for (int j = 0; j < 4; ++j) acc[2][j] += cv * b2f((unsigned short)v1[j]);
            #pragma unroll
            for (int j = 0; j < 4; ++j) acc[3][j] += cv * b2f((unsigned short)v1[4 + j]);
        }
        __syncthreads();   // ksh (K) fully consumed; xob may overwrite it
        #pragma unroll
        for (int k4 = 0; k4 < 4; ++k4) {
            u16x4 hb;
            hb[0] = (unsigned short)f2b(acc[k4][0]);
            hb[1] = (unsigned short)f2b(acc[k4][1]);
            hb[2] = (unsigned short)f2b(acc[k4][2]);
            hb[3] = (unsigned short)f2b(acc[k4][3]);
            *(u16x4*)&xob[r * 136 + cb + k4 * 4] = hb;
        }
    }
    __syncthreads();

    // ---------------- Phase 4: out = x_out @ Wproj^T + bproj (MFMA) -------
    {
        bf16x8 a2[2][4];
        #pragma unroll
        for (int kk = 0; kk < 4; ++kk) {
            a2[0][kk] = *(const bf16x8*)&xob[am * 136 + kk * 32 + ak];
            a2[1][kk] = *(const bf16x8*)&xob[(16 + am) * 136 + kk * 32 + ak];
        }
        float* ob = out + (size_t)b * BS * CH;
        #pragma unroll
        for (int ntl = 0; ntl < 2; ++ntl) {
            int col = (w * 2 + ntl) * 16 + colm;
            float bias = bproj[col];
            f32x4 acc0 = {bias, bias, bias, bias};
            f32x4 acc1 = acc0;
            #pragma unroll
            for (int kk = 0; kk < 4; ++kk) {
                bf16x8 bfr = *(const bf16x8*)(wproj_b + col * CH + kk * 32 + ak);
                acc0 = __builtin_amdgcn_mfma_f32_16x16x32_bf16(a2[0][kk], bfr, acc0, 0, 0, 0);
                acc1 = __builtin_amdgcn_mfma_f32_16x16x32_bf16(a2[1][kk], bfr, acc1, 0, 0, 0);
            }
            #pragma unroll
            for (int j = 0; j < 4; ++j) {
                ob[(rb + j) * CH + col]      = acc0[j];
                ob[(16 + rb + j) * CH + col] = acc1[j];
            }
        }
    }
}

extern "C" void kernel_launch(void* const* d_in, const int* in_sizes, int n_in,
                              void* d_out, int out_size, void* d_ws, size_t ws_size,
                              hipStream_t stream) {
    const float* x          = (const float*)d_in[0];
    const float* edge_feats = (const float*)d_in[1];
    const float* Wqkv       = (const float*)d_in[2];
    const float* bqkv       = (const float*)d_in[3];
    const float* Wproj      = (const float*)d_in[4];
    const float* bproj      = (const float*)d_in[5];
    const float* Wgate      = (const float*)d_in[6];
    const float* bgate      = (const float*)d_in[7];
    const int*   attn_mask  = (const int*)d_in[8];
    float* out = (float*)d_out;
    short* wb  = (short*)d_ws;

    convert_weights<<<256, 256, 0, stream>>>(Wqkv, Wproj, wb);
    fused_block_attn<<<NBLK, 256, 0, stream>>>(
        x, edge_feats, bqkv, bproj, Wgate, bgate, attn_mask,
        wb, wb + 3 * CH * CH, out);
}

// Round 3
// 95.868 us; speedup vs baseline: 14.7236x; 1.5553x over previous
//
#include <hip/hip_runtime.h>
#include <hip/hip_bf16.h>

#define NBLK 4096
#define BS 32
#define CH 128

typedef float f32x4 __attribute__((ext_vector_type(4)));
typedef short bf16x8 __attribute__((ext_vector_type(8)));
typedef unsigned short u16x4 __attribute__((ext_vector_type(4)));

__device__ __forceinline__ short f2b(float x) {
    union { float f; unsigned u; } c; c.f = x;
    unsigned r = c.u + 0x7fffu + ((c.u >> 16) & 1u);
    return (short)(r >> 16);
}
__device__ __forceinline__ float b2f(unsigned short h) {
    union { unsigned u; float f; } c; c.u = ((unsigned)h) << 16; return c.f;
}
__device__ __forceinline__ u16x4 pack4(f32x4 a) {
    u16x4 o;
    o[0] = (unsigned short)f2b(a[0]);
    o[1] = (unsigned short)f2b(a[1]);
    o[2] = (unsigned short)f2b(a[2]);
    o[3] = (unsigned short)f2b(a[3]);
    return o;
}

// --- pre-kernel: convert weights to bf16 into workspace -------------------
__global__ void convert_weights(const float* __restrict__ wqkv,
                                const float* __restrict__ wproj,
                                short* __restrict__ wsout) {
    int i = blockIdx.x * 256 + threadIdx.x;          // 0 .. 65535
    if (i < 3 * CH * CH) {
        wsout[i] = f2b(wqkv[i]);
    } else {
        int j = i - 3 * CH * CH;
        if (j < CH * CH) wsout[3 * CH * CH + j] = f2b(wproj[j]);
    }
}

// Layout rule used throughout (verified by R1/R2 passing kernel):
//   mfma_f32_16x16x32_bf16(P, Q, C) with P read from matP[lane&15][k],
//   Q read from matQ[lane&15][k] (k = (lane>>4)*8 + j) gives
//   D[i][j] = sum_k matP[i][k]*matQ[j][k], col(lane&15)=j (Q row index),
//   row((lane>>4)*4+jj)=i (P row index).
//
// LDS plan (39,424 B -> 4 blocks/CU):
//   regionA [32][136] bf16 (8704): x-staging (kv) -> x_out (PV output)
//   qs [4][32][40] bf16 (10240)  : Q rows per head
//   kc [4] chunks of [32][40]    : K rows per head -> combined (overwrite)
//   vt [4][32][40] bf16 (10240)  : V^T per head ([d][s])
__launch_bounds__(256, 4)
__global__ void fused_block_attn(
    const float* __restrict__ x,
    const float* __restrict__ edge_feats,
    const float* __restrict__ bqkv,
    const float* __restrict__ bproj,
    const float* __restrict__ wgate,
    const float* __restrict__ bgate,
    const int*   __restrict__ attn_mask,
    const short* __restrict__ wqkv_b,    // [384][128] bf16
    const short* __restrict__ wproj_b,   // [128][128] bf16
    float* __restrict__ out)
{
    const int b    = blockIdx.x;
    const int tid  = threadIdx.x;
    const int lane = tid & 63;
    const int w    = tid >> 6;
    const int lm   = lane & 15;        // row-in-tile for both operands
    const int g    = lane >> 4;
    const int ak   = g * 8;            // k-offset within K=32
    const int rb   = g * 4;            // D-row base within tile

    __shared__ short regionA[32 * 136];     // kvb -> xob
    __shared__ short qs[4 * 32 * 40];
    __shared__ short kc[4 * 32 * 40];       // ks -> comb (per-head 1280-short chunks)
    __shared__ short vt[4 * 32 * 40];

    // ---------------- Phase 0: stage x as bf16 ----------------------------
    const float* xb = x + (size_t)b * BS * CH;
    #pragma unroll
    for (int it = 0; it < 4; ++it) {
        int idx = tid + it * 256;            // f32x4 index
        int r   = idx >> 5;
        int c4  = idx & 31;
        f32x4 t = ((const f32x4*)xb)[idx];
        *(u16x4*)&regionA[r * 136 + c4 * 4] = pack4(t);
    }
    __syncthreads();

    // ---------------- Phase 1: QKV GEMM (all stores packed) ---------------
    bf16x8 kvf[2][4];
    #pragma unroll
    for (int kk = 0; kk < 4; ++kk) {
        kvf[0][kk] = *(const bf16x8*)&regionA[lm * 136 + kk * 32 + ak];
        kvf[1][kk] = *(const bf16x8*)&regionA[(16 + lm) * 136 + kk * 32 + ak];
    }

    #pragma unroll
    for (int ntl = 0; ntl < 6; ++ntl) {
        const int nt = w * 6 + ntl;
        const int o0 = nt * 16;
        const short* wp = wqkv_b + (o0 + lm) * CH + ak;
        bf16x8 wf[4];
        #pragma unroll
        for (int kk = 0; kk < 4; ++kk) wf[kk] = *(const bf16x8*)(wp + kk * 32);

        const int h  = (o0 >> 5) & 3;
        if (nt < 16) {
            // q/k: swapped orientation -> D[outcol][token]
            f32x4 a0 = *(const f32x4*)(bqkv + o0 + rb);   // bias per D-row
            f32x4 a1 = a0;
            #pragma unroll
            for (int kk = 0; kk < 4; ++kk) {
                a0 = __builtin_amdgcn_mfma_f32_16x16x32_bf16(wf[kk], kvf[0][kk], a0, 0, 0, 0);
                a1 = __builtin_amdgcn_mfma_f32_16x16x32_bf16(wf[kk], kvf[1][kk], a1, 0, 0, 0);
            }
            const int d0 = (o0 & 31) + rb;
            short* dst = ((nt < 8) ? qs : kc) + h * 1280;
            *(u16x4*)&dst[lm * 40 + d0]        = pack4(a0);   // token=lm
            *(u16x4*)&dst[(16 + lm) * 40 + d0] = pack4(a1);   // token=16+lm
        } else {
            // v: normal orientation -> D[token][outcol], store V^T packed
            float bv = bqkv[o0 + lm];
            f32x4 a0 = {bv, bv, bv, bv};
            f32x4 a1 = a0;
            #pragma unroll
            for (int kk = 0; kk < 4; ++kk) {
                a0 = __builtin_amdgcn_mfma_f32_16x16x32_bf16(kvf[0][kk], wf[kk], a0, 0, 0, 0);
                a1 = __builtin_amdgcn_mfma_f32_16x16x32_bf16(kvf[1][kk], wf[kk], a1, 0, 0, 0);
            }
            const int d0 = (o0 & 31) + lm;
            short* dst = vt + h * 1280;
            *(u16x4*)&dst[d0 * 40 + rb]      = pack4(a0);     // s=rb..rb+3
            *(u16x4*)&dst[d0 * 40 + 16 + rb] = pack4(a1);     // s=16+rb..
        }
    }
    __syncthreads();

    // ---------------- Phase 2a: scores^T via MFMA, per head ---------------
    {
        const int h = w;
        const short* ksh = kc + h * 1280;
        const short* qsh = qs + h * 1280;
        bf16x8 af0 = *(const bf16x8*)&ksh[lm * 40 + ak];          // K rows s
        bf16x8 af1 = *(const bf16x8*)&ksh[(16 + lm) * 40 + ak];
        bf16x8 bf0 = *(const bf16x8*)&qsh[lm * 40 + ak];          // Q rows q
        bf16x8 bf1 = *(const bf16x8*)&qsh[(16 + lm) * 40 + ak];
        f32x4 z = {0.f, 0.f, 0.f, 0.f};
        f32x4 s00 = __builtin_amdgcn_mfma_f32_16x16x32_bf16(af0, bf0, z, 0, 0, 0); // D[s0-15][q0-15]
        f32x4 s10 = __builtin_amdgcn_mfma_f32_16x16x32_bf16(af1, bf0, z, 0, 0, 0); // s16-31
        f32x4 s01 = __builtin_amdgcn_mfma_f32_16x16x32_bf16(af0, bf1, z, 0, 0, 0); // q16-31
        f32x4 s11 = __builtin_amdgcn_mfma_f32_16x16x32_bf16(af1, bf1, z, 0, 0, 0);
        const float SC = 0.17677669529663689f;
        short* ch = kc + h * 1280;               // comb chunk overwrites ks (in-wave safe)
        *(u16x4*)&ch[lm * 40 + rb]             = pack4(s00 * SC); // comb[q][s]
        *(u16x4*)&ch[lm * 40 + 16 + rb]        = pack4(s10 * SC);
        *(u16x4*)&ch[(16 + lm) * 40 + rb]      = pack4(s01 * SC);
        *(u16x4*)&ch[(16 + lm) * 40 + 16 + rb] = pack4(s11 * SC);
    }
    __syncthreads();

    // ---------------- Phase 2b: softmax + edge gate (256 thr) -------------
    {
        const int r    = tid >> 3;
        const int h    = (tid >> 1) & 3;
        const int half = tid & 1;
        short* ch = kc + h * 1280;

        bf16x8 t0 = *(const bf16x8*)&ch[r * 40 + half * 16];
        bf16x8 t1 = *(const bf16x8*)&ch[r * 40 + half * 16 + 8];
        float d[16];
        #pragma unroll
        for (int j = 0; j < 8; ++j) { d[j] = b2f((unsigned short)t0[j]); d[8 + j] = b2f((unsigned short)t1[j]); }

        float sd = 0.f;
        #pragma unroll
        for (int j = 0; j < 16; ++j) sd += d[j];
        sd += __shfl_xor(sd, 1);
        const float d32 = sd * 0.03125f;         // scaled dot for global token

        const float* efb = edge_feats + ((size_t)(b * BS + r)) * 33 * 4 + half * 64;
        const int*   mk  = attn_mask + (size_t)(b * BS + r) * 33 + half * 16;
        f32x4 wg = *(const f32x4*)(wgate + h * 4);
        float bg = bgate[h];

        float sc[16], lw[16];
        float mx = -3.0e38f;
        #pragma unroll
        for (int s = 0; s < 16; ++s) {
            int sg = half * 16 + s;
            f32x4 ef = *(const f32x4*)(efb + s * 4);
            if (sg == r) { ef[0] = 0.f; ef[1] = 0.f; ef[2] = 0.f; ef[3] = 1.f; }
            int m = mk[s];
            sc[s] = m ? (d[s] + ef[3]) : -1.0e30f;
            lw[s] = m ? (ef[0] * wg[0] + ef[1] * wg[1] + ef[2] * wg[2] + ef[3] * wg[3] + bg) : 0.f;
            mx = fmaxf(mx, sc[s]);
        }
        mx = fmaxf(mx, __shfl_xor(mx, 1));
        const float sc32 = d32 + 1.0f;           // global token: ef=(0,0,0,1), mask=1
        mx = fmaxf(mx, sc32);

        float se = 0.f;
        #pragma unroll
        for (int s = 0; s < 16; ++s) {
            float e = __expf(sc[s] - mx);
            sc[s] = e;
            se += e;
        }
        const float e32 = __expf(sc32 - mx);
        const float tot = se + __shfl_xor(se, 1) + e32;
        const float rinv = 1.0f / tot;
        const float add32 = (e32 * rinv + (wg[3] + bg)) * 0.03125f;  // fold global token

        #pragma unroll
        for (int pk = 0; pk < 4; ++pk) {
            u16x4 o;
            #pragma unroll
            for (int j = 0; j < 4; ++j) {
                float v = sc[pk * 4 + j] * rinv + lw[pk * 4 + j] + add32;
                o[j] = (unsigned short)f2b(v);
            }
            *(u16x4*)&ch[r * 40 + half * 16 + pk * 4] = o;
        }
    }
    __syncthreads();

    // ---------------- Phase 3: PV via MFMA, per head -----------------------
    {
        const int h = w;
        const short* ch  = kc + h * 1280;
        const short* vth = vt + h * 1280;
        bf16x8 av0 = *(const bf16x8*)&vth[lm * 40 + ak];          // V^T rows d
        bf16x8 av1 = *(const bf16x8*)&vth[(16 + lm) * 40 + ak];
        bf16x8 bc0 = *(const bf16x8*)&ch[lm * 40 + ak];           // comb rows q
        bf16x8 bc1 = *(const bf16x8*)&ch[(16 + lm) * 40 + ak];
        f32x4 z = {0.f, 0.f, 0.f, 0.f};
        f32x4 x00 = __builtin_amdgcn_mfma_f32_16x16x32_bf16(av0, bc0, z, 0, 0, 0); // D[d0-15][q0-15]
        f32x4 x10 = __builtin_amdgcn_mfma_f32_16x16x32_bf16(av1, bc0, z, 0, 0, 0);
        f32x4 x01 = __builtin_amdgcn_mfma_f32_16x16x32_bf16(av0, bc1, z, 0, 0, 0);
        f32x4 x11 = __builtin_amdgcn_mfma_f32_16x16x32_bf16(av1, bc1, z, 0, 0, 0);
        short* xob = regionA;                     // overwrite x-staging
        *(u16x4*)&xob[lm * 136 + h * 32 + rb]             = pack4(x00);  // [q][h*32+d]
        *(u16x4*)&xob[lm * 136 + h * 32 + 16 + rb]        = pack4(x10);
        *(u16x4*)&xob[(16 + lm) * 136 + h * 32 + rb]      = pack4(x01);
        *(u16x4*)&xob[(16 + lm) * 136 + h * 32 + 16 + rb] = pack4(x11);
    }
    __syncthreads();

    // ---------------- Phase 4: out = x_out @ Wproj^T + bproj --------------
    {
        const short* xob = regionA;
        bf16x8 a2[2][4];
        #pragma unroll
        for (int kk = 0; kk < 4; ++kk) {
            a2[0][kk] = *(const bf16x8*)&xob[lm * 136 + kk * 32 + ak];
            a2[1][kk] = *(const bf16x8*)&xob[(16 + lm) * 136 + kk * 32 + ak];
        }
        float* ob = out + (size_t)b * BS * CH;
        #pragma unroll
        for (int ntl = 0; ntl < 2; ++ntl) {
            int col = (w * 2 + ntl) * 16 + lm;
            float bias = bproj[col];
            f32x4 acc0 = {bias, bias, bias, bias};
            f32x4 acc1 = acc0;
            #pragma unroll
            for (int kk = 0; kk < 4; ++kk) {
                bf16x8 bfr = *(const bf16x8*)(wproj_b + col * CH + kk * 32 + ak);
                acc0 = __builtin_amdgcn_mfma_f32_16x16x32_bf16(a2[0][kk], bfr, acc0, 0, 0, 0);
                acc1 = __builtin_amdgcn_mfma_f32_16x16x32_bf16(a2[1][kk], bfr, acc1, 0, 0, 0);
            }
            #pragma unroll
            for (int j = 0; j < 4; ++j) {
                ob[(rb + j) * CH + col]      = acc0[j];
                ob[(16 + rb + j) * CH + col] = acc1[j];
            }
        }
    }
}

extern "C" void kernel_launch(void* const* d_in, const int* in_sizes, int n_in,
                              void* d_out, int out_size, void* d_ws, size_t ws_size,
                              hipStream_t stream) {
    const float* x          = (const float*)d_in[0];
    const float* edge_feats = (const float*)d_in[1];
    const float* Wqkv       = (const float*)d_in[2];
    const float* bqkv       = (const float*)d_in[3];
    const float* Wproj      = (const float*)d_in[4];
    const float* bproj      = (const float*)d_in[5];
    const float* Wgate      = (const float*)d_in[6];
    const float* bgate      = (const float*)d_in[7];
    const int*   attn_mask  = (const int*)d_in[8];
    float* out = (float*)d_out;
    short* wb  = (short*)d_ws;

    convert_weights<<<256, 256, 0, stream>>>(Wqkv, Wproj, wb);
    fused_block_attn<<<NBLK, 256, 0, stream>>>(
        x, edge_feats, bqkv, bproj, Wgate, bgate, attn_mask,
        wb, wb + 3 * CH * CH, out);
}